// Round 8
// baseline (1426.423 us; speedup 1.0000x reference)
//
#include <hip/hip_runtime.h>
#include <stdint.h>

typedef unsigned short u16;
typedef unsigned int   u32;
typedef float   f32x4  __attribute__((ext_vector_type(4)));
typedef float   f32x16 __attribute__((ext_vector_type(16)));
typedef __bf16  bf16x8 __attribute__((ext_vector_type(8)));
typedef u32     u32x4  __attribute__((ext_vector_type(4)));
typedef u32     u32x2  __attribute__((ext_vector_type(2)));

union BF8 { bf16x8 v; u16 s[8]; u32x4 q; };

__device__ __forceinline__ u16 f2b_rne(float f) {
    u32 u = __builtin_bit_cast(u32, f);
    u32 r = u + 0x7FFFu + ((u >> 16) & 1u);
    return (u16)(r >> 16);
}
__device__ __forceinline__ u16 f2b_trunc(float f) {
    return (u16)(__builtin_bit_cast(u32, f) >> 16);
}
__device__ __forceinline__ float b2f(u16 h) {
    u32 u = ((u32)h) << 16;
    return __builtin_bit_cast(float, u);
}
__device__ __forceinline__ bf16x8 ld_bf8(const u16* p) {
    BF8 t; t.q = *(const u32x4*)p; return t.v;
}
__device__ __forceinline__ f32x16 zero16() {
    f32x16 z;
#pragma unroll
    for (int i = 0; i < 16; i++) z[i] = 0.f;
    return z;
}
__device__ __forceinline__ f32x4 zero4() {
    f32x4 z;
#pragma unroll
    for (int i = 0; i < 4; i++) z[i] = 0.f;
    return z;
}

#define SCALE2 0.1275312959479341f        /* log2(e)/sqrt(128) */
#define MBIAS2 -1442.6950408889634f       /* -1000*log2(e) */

// ---------------------------------------------------------------------------
// projection: W columns read coalesced (lane-consecutive c) and hi/lo split
// in-reg. Q/K written hi/lo head-packed [b][h][s][16] (Q pre-scaled by
// log2e/sqrt(128)); V written transposed VT[b*128+n][s]. grid (256,3) x 256.
// ---------------------------------------------------------------------------
__global__ __launch_bounds__(256) void proj_kernel(
    const float* __restrict__ x, const float* __restrict__ wq,
    const float* __restrict__ wk, const float* __restrict__ wv,
    u16* Qph, u16* Qpl, u16* Kph, u16* Kpl, u16* VT)
{
    int typ  = blockIdx.y;                 // 0=Q 1=K 2=V
    int ct   = threadIdx.x >> 6;
    int lane = threadIdx.x & 63;
    int m = lane & 31, kg = lane >> 5;
    int r0 = blockIdx.x * 32;
    int c = ct * 32 + m;

    const float* wp = (typ == 0) ? wq : (typ == 1) ? wk : wv;

    f32x16 acc = zero16();
#pragma unroll 4
    for (int kk = 0; kk < 128; kk += 16) {
        const float* xp = x + (size_t)(r0 + m) * 128 + kk + kg * 8;
        f32x4 x0 = *(const f32x4*)xp;
        f32x4 x1 = *(const f32x4*)(xp + 4);
        BF8 ah, al;
#pragma unroll
        for (int j = 0; j < 4; j++) {
            u16 hb = f2b_trunc(x0[j]);
            ah.s[j] = hb; al.s[j] = f2b_trunc(x0[j] - b2f(hb));
            u16 hb2 = f2b_trunc(x1[j]);
            ah.s[4 + j] = hb2; al.s[4 + j] = f2b_trunc(x1[j] - b2f(hb2));
        }
        const float* wcol = wp + (size_t)(kk + kg * 8) * 128 + c;
        if (typ < 2) {
            BF8 bh, bl_;
#pragma unroll
            for (int j = 0; j < 8; j++) {
                float w = wcol[(size_t)j * 128];
                u16 hb = f2b_trunc(w);
                bh.s[j] = hb; bl_.s[j] = f2b_trunc(w - b2f(hb));
            }
            acc = __builtin_amdgcn_mfma_f32_32x32x16_bf16(ah.v, bh.v, acc, 0, 0, 0);
            acc = __builtin_amdgcn_mfma_f32_32x32x16_bf16(ah.v, bl_.v, acc, 0, 0, 0);
            acc = __builtin_amdgcn_mfma_f32_32x32x16_bf16(al.v, bh.v, acc, 0, 0, 0);
        } else {
            BF8 bh;
#pragma unroll
            for (int j = 0; j < 8; j++) bh.s[j] = f2b_rne(wcol[(size_t)j * 128]);
            acc = __builtin_amdgcn_mfma_f32_32x32x16_bf16(ah.v, bh.v, acc, 0, 0, 0);
        }
    }

    int b = r0 >> 11, sl = r0 & 2047;
    if (typ < 2) {
        u16* H = typ ? Kph : Qph;
        u16* L = typ ? Kpl : Qpl;
        int hh = c >> 4, d = c & 15;
        if (hh == 7) return;                      // head 7 never consumed
        float scl = (typ == 0) ? SCALE2 : 1.0f;
        size_t hb_off = (size_t)(b * 8 + hh) * 2048 * 16 + d;
#pragma unroll
        for (int r = 0; r < 16; r++) {
            int row = (r & 3) + 8 * (r >> 2) + 4 * kg;
            float v = acc[r] * scl;
            u16 hi = f2b_trunc(v);
            size_t idx = hb_off + (size_t)(sl + row) * 16;
            H[idx] = hi;
            L[idx] = f2b_trunc(v - b2f(hi));
        }
    } else {
        if ((c >> 4) == 7) return;
#pragma unroll
        for (int rg = 0; rg < 4; rg++) {
            int rowb = rg * 8 + 4 * kg;
            BF8 pk;
#pragma unroll
            for (int q = 0; q < 4; q++) pk.s[q] = f2b_rne(acc[rg * 4 + q]);
            u32x4 tmp = pk.q;
            *(u32*)(VT + (size_t)(b * 128 + c) * 2048 + sl + rowb)     = tmp[0];
            *(u32*)(VT + (size_t)(b * 128 + c) * 2048 + sl + rowb + 2) = tmp[1];
        }
    }
}

// ---------------------------------------------------------------------------
// fused attention (R7 + software-pipelined PV):
//  - S^T orientation (lane = query, keys in regs); soft mask bias staged in
//    LDS in MFMA C-layout; mrow pre-subtracted into the C operand so the
//    exp2 is a single op on the MFMA result.
//  - PV runs ONE TILE BEHIND: p0/p1/vf are loop-carried, so tile t-1's PV
//    MFMAs overlap tile t's ci-load/sub/score chain. Single pbuf is safe:
//    same-wave DS ops are in-order (read(t-1) completes before write(t)).
//  - pbuf stride 32 u16, XOR block swizzle (16B-aligned everything).
//  - K/V prefetch; 7 blocks/CU resident (grid 1792 = 7x256).
// ---------------------------------------------------------------------------
__global__ __launch_bounds__(256, 7) void attn_kernel(
    const u16* __restrict__ Qph, const u16* __restrict__ Qpl,
    const u16* __restrict__ Kph, const u16* __restrict__ Kpl,
    const u16* __restrict__ VT, const int* __restrict__ mask, u16* AO)
{
    __shared__ char smem[16896];
    u16*   pbuf  = (u16*)smem;               // [4][32][32] u16 = 8192 B (swizzled)
    float* biasC = (float*)(smem + 8192);    // [64 tiles][2 kg][16 reg] = 8192 B
    float* lsmax = (float*)(smem + 16384);   // [32][4] = 512 B
    float* obuf  = (float*)smem;             // [4][16][32] f32, aliases pbuf
    float* lbuf  = (float*)(smem + 8192);    // [4][32] f32, aliases biasC (dead)

    int bid = blockIdx.x;
    int bh = bid % 28;
    int qt = bid / 28;
    int b = bh / 7, h = bh % 7;
    int wave = threadIdx.x >> 6, lane = threadIdx.x & 63;
    int m = lane & 31, kg = lane >> 5;
    int qs = qt * 32;

    // ---- bias table in MFMA C-layout: entry e=(tile*32+kg*16+r)
    //      -> key tile*32 + (r&3)+8*(r>>2)+4*kg ----
    {
        int e0 = threadIdx.x * 8;
        const int* mp = mask + b * 2048;
        float v[8];
#pragma unroll
        for (int j = 0; j < 8; j++) {
            int e = e0 + j;
            int ti = e >> 5, kgg = (e >> 4) & 1, r = e & 15;
            int key = ti * 32 + (r & 3) + 8 * (r >> 2) + 4 * kgg;
            v[j] = (mp[key] != 0) ? 0.0f : MBIAS2;
        }
        *(f32x4*)(biasC + e0)     = *(const f32x4*)&v[0];
        *(f32x4*)(biasC + e0 + 4) = *(const f32x4*)&v[4];
    }
    __syncthreads();

    size_t headoff = (size_t)(b * 8 + h) * 2048 * 16;
    bf16x8 qfh = ld_bf8(Qph + headoff + (size_t)(qs + m) * 16 + kg * 8);
    bf16x8 qfl = ld_bf8(Qpl + headoff + (size_t)(qs + m) * 16 + kg * 8);
    const u16* kbh = Kph + headoff;
    const u16* kbl = Kpl + headoff;

    int t0 = wave * 512;

    // ---- pass 1: per-query max of approx biased scores (K hi x Q hi + bias) ----
    float mloc = -3.0e38f;
    {
        bf16x8 khc = ld_bf8(kbh + (size_t)(t0 + m) * 16 + kg * 8);
        for (int t = t0; t < t0 + 512; t += 32) {
            int tn = (t + 32 < t0 + 512) ? (t + 32) : t0;
            bf16x8 khn = ld_bf8(kbh + (size_t)(tn + m) * 16 + kg * 8);
            f32x16 ci = *(const f32x16*)(biasC + (t >> 5) * 32 + kg * 16);
            f32x16 sc = __builtin_amdgcn_mfma_f32_32x32x16_bf16(khc, qfh, ci, 0, 0, 0);
#pragma unroll
            for (int r = 0; r < 16; r += 2)       // paired for v_max3 fusion
                mloc = fmaxf(fmaxf(mloc, sc[r]), sc[r + 1]);
            khc = khn;
        }
    }
    mloc = fmaxf(mloc, __shfl_xor(mloc, 32, 64));
    if (kg == 0) lsmax[m * 4 + wave] = mloc;
    __syncthreads();
    f32x4 mv = *(const f32x4*)(lsmax + m * 4);
    float mrow = fmaxf(fmaxf(mv[0], mv[1]), fmaxf(mv[2], mv[3]));  // per-lane (query m)

    // ---- pass 2 (pipelined): scores(t) overlap PV(t-1) ----
    f32x4 o0 = zero4(), o1 = zero4(), l0 = zero4(), l1 = zero4();
    BF8 onesu;
#pragma unroll
    for (int j = 0; j < 8; j++) onesu.s[j] = 0x3F80;
    bf16x8 ones = onesu.v;

    int q16 = lane & 15, krow = lane >> 4;
    const u16* vtb = VT + (size_t)(b * 128 + h * 16 + q16) * 2048;
    int msw = (m >> 1) & 3;                                  // write swizzle
    int qsw = (q16 >> 1) & 3;                                // read swizzle
    u16* pwb = pbuf + wave * 1024 + m * 32 + kg * 4;
    const u16* pr0 = pbuf + wave * 1024 + q16 * 32 + ((krow ^ qsw) * 8);
    const u16* pr1 = pr0 + 16 * 32;

    bf16x8 khc = ld_bf8(kbh + (size_t)(t0 + m) * 16 + kg * 8);
    bf16x8 klc = ld_bf8(kbl + (size_t)(t0 + m) * 16 + kg * 8);
    bf16x8 p0c, p1c, vfc;

    // peeled first tile: score/exp/write/read only (no pending PV yet)
    {
        bf16x8 khn = ld_bf8(kbh + (size_t)(t0 + 32 + m) * 16 + kg * 8);
        bf16x8 kln = ld_bf8(kbl + (size_t)(t0 + 32 + m) * 16 + kg * 8);
        vfc = ld_bf8(vtb + t0 + krow * 8);
        f32x16 ci = *(const f32x16*)(biasC + (t0 >> 5) * 32 + kg * 16);
        f32x16 ci2;
#pragma unroll
        for (int r = 0; r < 16; r++) ci2[r] = ci[r] - mrow;
        f32x16 sc = __builtin_amdgcn_mfma_f32_32x32x16_bf16(khc, qfl, ci2, 0, 0, 0);
        sc = __builtin_amdgcn_mfma_f32_32x32x16_bf16(klc, qfh, sc, 0, 0, 0);
        sc = __builtin_amdgcn_mfma_f32_32x32x16_bf16(khc, qfh, sc, 0, 0, 0);
#pragma unroll
        for (int rg = 0; rg < 4; rg++) {
            float e0 = __builtin_amdgcn_exp2f(sc[rg * 4 + 0]);
            float e1 = __builtin_amdgcn_exp2f(sc[rg * 4 + 1]);
            float e2 = __builtin_amdgcn_exp2f(sc[rg * 4 + 2]);
            float e3 = __builtin_amdgcn_exp2f(sc[rg * 4 + 3]);
            u32x2 pk;
            pk[0] = __builtin_amdgcn_perm(__builtin_bit_cast(u32, e1),
                                          __builtin_bit_cast(u32, e0), 0x07060302u);
            pk[1] = __builtin_amdgcn_perm(__builtin_bit_cast(u32, e3),
                                          __builtin_bit_cast(u32, e2), 0x07060302u);
            *(u32x2*)(pwb + ((rg ^ msw) * 8)) = pk;
        }
        p0c = *(const bf16x8*)pr0;
        p1c = *(const bf16x8*)pr1;
        khc = khn; klc = kln;
    }

    for (int t = t0 + 32; t < t0 + 512; t += 32) {
        int tn = (t + 32 < t0 + 512) ? (t + 32) : t0;
        bf16x8 khn = ld_bf8(kbh + (size_t)(tn + m) * 16 + kg * 8);
        bf16x8 kln = ld_bf8(kbl + (size_t)(tn + m) * 16 + kg * 8);
        bf16x8 vfn = ld_bf8(vtb + t + krow * 8);
        f32x16 ci = *(const f32x16*)(biasC + (t >> 5) * 32 + kg * 16);
        f32x16 ci2;
#pragma unroll
        for (int r = 0; r < 16; r++) ci2[r] = ci[r] - mrow;

        // PV for the PREVIOUS tile (overlaps this tile's score chain)
        o0 = __builtin_amdgcn_mfma_f32_16x16x32_bf16(p0c, vfc, o0, 0, 0, 0);
        o1 = __builtin_amdgcn_mfma_f32_16x16x32_bf16(p1c, vfc, o1, 0, 0, 0);
        l0 = __builtin_amdgcn_mfma_f32_16x16x32_bf16(p0c, ones, l0, 0, 0, 0);
        l1 = __builtin_amdgcn_mfma_f32_16x16x32_bf16(p1c, ones, l1, 0, 0, 0);

        f32x16 sc = __builtin_amdgcn_mfma_f32_32x32x16_bf16(khc, qfl, ci2, 0, 0, 0);
        sc = __builtin_amdgcn_mfma_f32_32x32x16_bf16(klc, qfh, sc, 0, 0, 0);
        sc = __builtin_amdgcn_mfma_f32_32x32x16_bf16(khc, qfh, sc, 0, 0, 0);
#pragma unroll
        for (int rg = 0; rg < 4; rg++) {
            float e0 = __builtin_amdgcn_exp2f(sc[rg * 4 + 0]);
            float e1 = __builtin_amdgcn_exp2f(sc[rg * 4 + 1]);
            float e2 = __builtin_amdgcn_exp2f(sc[rg * 4 + 2]);
            float e3 = __builtin_amdgcn_exp2f(sc[rg * 4 + 3]);
            u32x2 pk;
            pk[0] = __builtin_amdgcn_perm(__builtin_bit_cast(u32, e1),
                                          __builtin_bit_cast(u32, e0), 0x07060302u);
            pk[1] = __builtin_amdgcn_perm(__builtin_bit_cast(u32, e3),
                                          __builtin_bit_cast(u32, e2), 0x07060302u);
            *(u32x2*)(pwb + ((rg ^ msw) * 8)) = pk;
        }
        p0c = *(const bf16x8*)pr0;
        p1c = *(const bf16x8*)pr1;
        vfc = vfn; khc = khn; klc = kln;
    }

    // drain the pipeline: final tile's PV
    o0 = __builtin_amdgcn_mfma_f32_16x16x32_bf16(p0c, vfc, o0, 0, 0, 0);
    o1 = __builtin_amdgcn_mfma_f32_16x16x32_bf16(p1c, vfc, o1, 0, 0, 0);
    l0 = __builtin_amdgcn_mfma_f32_16x16x32_bf16(p0c, ones, l0, 0, 0, 0);
    l1 = __builtin_amdgcn_mfma_f32_16x16x32_bf16(p1c, ones, l1, 0, 0, 0);

    __syncthreads();     // all P-tile reads done before obuf/lbuf alias writes

    *(f32x4*)(obuf + wave * 512 + q16 * 32 + krow * 4)      = o0;
    *(f32x4*)(obuf + wave * 512 + q16 * 32 + krow * 4 + 16) = o1;
    if (q16 == 0) {
        *(f32x4*)(lbuf + wave * 32 + krow * 4)      = l0;
        *(f32x4*)(lbuf + wave * 32 + krow * 4 + 16) = l1;
    }
    __syncthreads();

    int dd = threadIdx.x & 15, q = threadIdx.x >> 4;
    int slot0 = (h == 0) ? 0 : h + 1;
#pragma unroll
    for (int hf = 0; hf < 2; hf++) {
        int qq = q + hf * 16;
        float os = obuf[0 * 512 + dd * 32 + qq] + obuf[1 * 512 + dd * 32 + qq]
                 + obuf[2 * 512 + dd * 32 + qq] + obuf[3 * 512 + dd * 32 + qq];
        float ls = lbuf[0 * 32 + qq] + lbuf[1 * 32 + qq]
                 + lbuf[2 * 32 + qq] + lbuf[3 * 32 + qq];
        u16 vb = f2b_rne(os * __builtin_amdgcn_rcpf(ls));
        int orow = b * 2048 + qs + qq;
        AO[orow * 128 + slot0 * 16 + dd] = vb;
        if (h == 1) AO[orow * 128 + 16 + dd] = vb;
    }
}

// ---------------------------------------------------------------------------
// final linear: out = AO(bf16) @ lin_w^T + lin_b (lin_w converted in-reg).
// ---------------------------------------------------------------------------
__global__ __launch_bounds__(256) void fin_kernel(
    const u16* __restrict__ AO, const float* __restrict__ lw,
    const float* __restrict__ lb, float* out)
{
    int ct   = threadIdx.x >> 6;
    int lane = threadIdx.x & 63;
    int m = lane & 31, kg = lane >> 5;
    int r0 = blockIdx.x * 32;
    int c = ct * 32 + m;

    f32x16 acc = zero16();
#pragma unroll 4
    for (int kk = 0; kk < 128; kk += 16) {
        bf16x8 af = ld_bf8(AO + (size_t)(r0 + m) * 128 + kk + kg * 8);
        const float* wp = lw + (size_t)c * 128 + kk + kg * 8;
        f32x4 w0 = *(const f32x4*)wp;
        f32x4 w1 = *(const f32x4*)(wp + 4);
        BF8 bfr;
#pragma unroll
        for (int j = 0; j < 4; j++) {
            bfr.s[j]     = f2b_rne(w0[j]);
            bfr.s[4 + j] = f2b_rne(w1[j]);
        }
        acc = __builtin_amdgcn_mfma_f32_32x32x16_bf16(af, bfr.v, acc, 0, 0, 0);
    }
    float bias = lb[c];
#pragma unroll
    for (int r = 0; r < 16; r++) {
        int row = (r & 3) + 8 * (r >> 2) + 4 * kg;
        out[(size_t)(r0 + row) * 128 + c] = acc[r] + bias;
    }
}

// ---------------------------------------------------------------------------
extern "C" void kernel_launch(void* const* d_in, const int* in_sizes, int n_in,
                              void* d_out, int out_size, void* d_ws, size_t ws_size,
                              hipStream_t stream)
{
    const float* x    = (const float*)d_in[0];
    const int*   mask = (const int*)d_in[1];
    const float* wq   = (const float*)d_in[2];
    const float* wk   = (const float*)d_in[3];
    const float* wv   = (const float*)d_in[4];
    const float* lw   = (const float*)d_in[5];
    const float* lb   = (const float*)d_in[6];
    float* out = (float*)d_out;

    char* ws = (char*)d_ws;
    u16* Qph = (u16*)(ws + 0 * 2097152);
    u16* Qpl = (u16*)(ws + 1 * 2097152);
    u16* Kph = (u16*)(ws + 2 * 2097152);
    u16* Kpl = (u16*)(ws + 3 * 2097152);
    u16* VT  = (u16*)(ws + 4 * 2097152);
    u16* AO  = (u16*)(ws + 5 * 2097152);

    proj_kernel<<<dim3(256, 3), 256, 0, stream>>>(x, wq, wk, wv,
                                                  Qph, Qpl, Kph, Kpl, VT);
    attn_kernel<<<1792, 256, 0, stream>>>(Qph, Qpl, Kph, Kpl, VT, mask, AO);
    fin_kernel<<<256, 256, 0, stream>>>(AO, lw, lb, out);
}

// Round 9
// 154.590 us; speedup vs baseline: 9.2271x; 9.2271x over previous
//
#include <hip/hip_runtime.h>
#include <stdint.h>

typedef unsigned short u16;
typedef unsigned int   u32;
typedef float   f32x4  __attribute__((ext_vector_type(4)));
typedef float   f32x16 __attribute__((ext_vector_type(16)));
typedef __bf16  bf16x8 __attribute__((ext_vector_type(8)));
typedef u32     u32x4  __attribute__((ext_vector_type(4)));
typedef u32     u32x2  __attribute__((ext_vector_type(2)));

union BF8 { bf16x8 v; u16 s[8]; u32x4 q; };

__device__ __forceinline__ u16 f2b_rne(float f) {
    u32 u = __builtin_bit_cast(u32, f);
    u32 r = u + 0x7FFFu + ((u >> 16) & 1u);
    return (u16)(r >> 16);
}
__device__ __forceinline__ u16 f2b_trunc(float f) {
    return (u16)(__builtin_bit_cast(u32, f) >> 16);
}
__device__ __forceinline__ float b2f(u16 h) {
    u32 u = ((u32)h) << 16;
    return __builtin_bit_cast(float, u);
}
__device__ __forceinline__ bf16x8 ld_bf8(const u16* p) {
    BF8 t; t.q = *(const u32x4*)p; return t.v;
}
__device__ __forceinline__ f32x16 zero16() {
    f32x16 z;
#pragma unroll
    for (int i = 0; i < 16; i++) z[i] = 0.f;
    return z;
}
__device__ __forceinline__ f32x4 zero4() {
    f32x4 z;
#pragma unroll
    for (int i = 0; i < 4; i++) z[i] = 0.f;
    return z;
}

#define SCALE2 0.1275312959479341f        /* log2(e)/sqrt(128) */
#define MBIAS2 -1442.6950408889634f       /* -1000*log2(e) */

// ---------------------------------------------------------------------------
// projection: W columns read coalesced (lane-consecutive c) and hi/lo split
// in-reg. Q/K written hi/lo head-packed [b][h][s][16] (Q pre-scaled by
// log2e/sqrt(128)); V written transposed VT[b*128+n][s]. grid (256,3) x 256.
// ---------------------------------------------------------------------------
__global__ __launch_bounds__(256) void proj_kernel(
    const float* __restrict__ x, const float* __restrict__ wq,
    const float* __restrict__ wk, const float* __restrict__ wv,
    u16* Qph, u16* Qpl, u16* Kph, u16* Kpl, u16* VT)
{
    int typ  = blockIdx.y;                 // 0=Q 1=K 2=V
    int ct   = threadIdx.x >> 6;
    int lane = threadIdx.x & 63;
    int m = lane & 31, kg = lane >> 5;
    int r0 = blockIdx.x * 32;
    int c = ct * 32 + m;

    const float* wp = (typ == 0) ? wq : (typ == 1) ? wk : wv;

    f32x16 acc = zero16();
#pragma unroll 4
    for (int kk = 0; kk < 128; kk += 16) {
        const float* xp = x + (size_t)(r0 + m) * 128 + kk + kg * 8;
        f32x4 x0 = *(const f32x4*)xp;
        f32x4 x1 = *(const f32x4*)(xp + 4);
        BF8 ah, al;
#pragma unroll
        for (int j = 0; j < 4; j++) {
            u16 hb = f2b_trunc(x0[j]);
            ah.s[j] = hb; al.s[j] = f2b_trunc(x0[j] - b2f(hb));
            u16 hb2 = f2b_trunc(x1[j]);
            ah.s[4 + j] = hb2; al.s[4 + j] = f2b_trunc(x1[j] - b2f(hb2));
        }
        const float* wcol = wp + (size_t)(kk + kg * 8) * 128 + c;
        if (typ < 2) {
            BF8 bh, bl_;
#pragma unroll
            for (int j = 0; j < 8; j++) {
                float w = wcol[(size_t)j * 128];
                u16 hb = f2b_trunc(w);
                bh.s[j] = hb; bl_.s[j] = f2b_trunc(w - b2f(hb));
            }
            acc = __builtin_amdgcn_mfma_f32_32x32x16_bf16(ah.v, bh.v, acc, 0, 0, 0);
            acc = __builtin_amdgcn_mfma_f32_32x32x16_bf16(ah.v, bl_.v, acc, 0, 0, 0);
            acc = __builtin_amdgcn_mfma_f32_32x32x16_bf16(al.v, bh.v, acc, 0, 0, 0);
        } else {
            BF8 bh;
#pragma unroll
            for (int j = 0; j < 8; j++) bh.s[j] = f2b_rne(wcol[(size_t)j * 128]);
            acc = __builtin_amdgcn_mfma_f32_32x32x16_bf16(ah.v, bh.v, acc, 0, 0, 0);
        }
    }

    int b = r0 >> 11, sl = r0 & 2047;
    if (typ < 2) {
        u16* H = typ ? Kph : Qph;
        u16* L = typ ? Kpl : Qpl;
        int hh = c >> 4, d = c & 15;
        if (hh == 7) return;                      // head 7 never consumed
        float scl = (typ == 0) ? SCALE2 : 1.0f;
        size_t hb_off = (size_t)(b * 8 + hh) * 2048 * 16 + d;
#pragma unroll
        for (int r = 0; r < 16; r++) {
            int row = (r & 3) + 8 * (r >> 2) + 4 * kg;
            float v = acc[r] * scl;
            u16 hi = f2b_trunc(v);
            size_t idx = hb_off + (size_t)(sl + row) * 16;
            H[idx] = hi;
            L[idx] = f2b_trunc(v - b2f(hi));
        }
    } else {
        if ((c >> 4) == 7) return;
#pragma unroll
        for (int rg = 0; rg < 4; rg++) {
            int rowb = rg * 8 + 4 * kg;
            BF8 pk;
#pragma unroll
            for (int q = 0; q < 4; q++) pk.s[q] = f2b_rne(acc[rg * 4 + q]);
            u32x4 tmp = pk.q;
            *(u32*)(VT + (size_t)(b * 128 + c) * 2048 + sl + rowb)     = tmp[0];
            *(u32*)(VT + (size_t)(b * 128 + c) * 2048 + sl + rowb + 2) = tmp[1];
        }
    }
}

// ---------------------------------------------------------------------------
// fused attention (R7 base + register-neutral PV pipeline):
//  - S^T orientation (lane = query, keys in regs); bias in LDS in MFMA
//    C-layout fed as the C operand; exp2(sc - mrow) computed directly
//    (NO ci2 pre-subtraction — that 16-reg live range caused R8's scratch
//    spill: FETCH_SIZE 7.3MB -> 4.15GB).
//  - l computed as in-register fp32 sums of e (frees 8 AGPR + 4 VGPR vs
//    the ones-MFMA pair — pays for the pipeline carries).
//  - PV runs one tile behind (carried p0c/p1c/vfc); single pbuf safe via
//    same-wave in-order DS.
//  - pbuf stride 32 u16 + XOR block swizzle (all 16B-aligned).
//  - 7 blocks/CU resident (grid 1792 = 7x256).
// ---------------------------------------------------------------------------
__global__ __launch_bounds__(256, 7) void attn_kernel(
    const u16* __restrict__ Qph, const u16* __restrict__ Qpl,
    const u16* __restrict__ Kph, const u16* __restrict__ Kpl,
    const u16* __restrict__ VT, const int* __restrict__ mask, u16* AO)
{
    __shared__ char smem[16896];
    u16*   pbuf  = (u16*)smem;               // [4][32][32] u16 = 8192 B (swizzled)
    float* biasC = (float*)(smem + 8192);    // [64 tiles][2 kg][16 reg] = 8192 B
    float* lsmax = (float*)(smem + 16384);   // [32][4] = 512 B
    float* obuf  = (float*)smem;             // [4][16][32] f32, aliases pbuf
    float* lbuf  = (float*)(smem + 8192);    // [4][32] f32, aliases biasC (dead)

    int bid = blockIdx.x;
    int bh = bid % 28;
    int qt = bid / 28;
    int b = bh / 7, h = bh % 7;
    int wave = threadIdx.x >> 6, lane = threadIdx.x & 63;
    int m = lane & 31, kg = lane >> 5;
    int qs = qt * 32;

    // ---- bias table in MFMA C-layout: entry e=(tile*32+kg*16+r)
    //      -> key tile*32 + (r&3)+8*(r>>2)+4*kg ----
    {
        int e0 = threadIdx.x * 8;
        const int* mp = mask + b * 2048;
        float v[8];
#pragma unroll
        for (int j = 0; j < 8; j++) {
            int e = e0 + j;
            int ti = e >> 5, kgg = (e >> 4) & 1, r = e & 15;
            int key = ti * 32 + (r & 3) + 8 * (r >> 2) + 4 * kgg;
            v[j] = (mp[key] != 0) ? 0.0f : MBIAS2;
        }
        *(f32x4*)(biasC + e0)     = *(const f32x4*)&v[0];
        *(f32x4*)(biasC + e0 + 4) = *(const f32x4*)&v[4];
    }
    __syncthreads();

    size_t headoff = (size_t)(b * 8 + h) * 2048 * 16;
    bf16x8 qfh = ld_bf8(Qph + headoff + (size_t)(qs + m) * 16 + kg * 8);
    bf16x8 qfl = ld_bf8(Qpl + headoff + (size_t)(qs + m) * 16 + kg * 8);
    const u16* kbh = Kph + headoff;
    const u16* kbl = Kpl + headoff;

    int t0 = wave * 512;

    // ---- pass 1: per-query max of approx biased scores (K hi x Q hi + bias) ----
    float mloc = -3.0e38f;
    {
        bf16x8 khc = ld_bf8(kbh + (size_t)(t0 + m) * 16 + kg * 8);
        for (int t = t0; t < t0 + 512; t += 32) {
            int tn = (t + 32 < t0 + 512) ? (t + 32) : t0;
            bf16x8 khn = ld_bf8(kbh + (size_t)(tn + m) * 16 + kg * 8);
            f32x16 ci = *(const f32x16*)(biasC + (t >> 5) * 32 + kg * 16);
            f32x16 sc = __builtin_amdgcn_mfma_f32_32x32x16_bf16(khc, qfh, ci, 0, 0, 0);
#pragma unroll
            for (int r = 0; r < 16; r += 2)       // paired for v_max3 fusion
                mloc = fmaxf(fmaxf(mloc, sc[r]), sc[r + 1]);
            khc = khn;
        }
    }
    mloc = fmaxf(mloc, __shfl_xor(mloc, 32, 64));
    if (kg == 0) lsmax[m * 4 + wave] = mloc;
    __syncthreads();
    f32x4 mv = *(const f32x4*)(lsmax + m * 4);
    float mrow = fmaxf(fmaxf(mv[0], mv[1]), fmaxf(mv[2], mv[3]));  // per-lane (query m)

    // ---- pass 2 (pipelined): scores(t) overlap PV(t-1) ----
    f32x4 o0 = zero4(), o1 = zero4();
    float lacc = 0.f;

    int q16 = lane & 15, krow = lane >> 4;
    const u16* vtb = VT + (size_t)(b * 128 + h * 16 + q16) * 2048;
    int msw = (m >> 1) & 3;                                  // write swizzle
    int qsw = (q16 >> 1) & 3;                                // read swizzle
    u16* pwb = pbuf + wave * 1024 + m * 32 + kg * 4;
    const u16* pr0 = pbuf + wave * 1024 + q16 * 32 + ((krow ^ qsw) * 8);
    const u16* pr1 = pr0 + 16 * 32;

    bf16x8 khc = ld_bf8(kbh + (size_t)(t0 + m) * 16 + kg * 8);
    bf16x8 klc = ld_bf8(kbl + (size_t)(t0 + m) * 16 + kg * 8);
    bf16x8 p0c, p1c, vfc;

    // peeled first tile: score/exp/write/read only (no pending PV yet)
    {
        bf16x8 khn = ld_bf8(kbh + (size_t)(t0 + 32 + m) * 16 + kg * 8);
        bf16x8 kln = ld_bf8(kbl + (size_t)(t0 + 32 + m) * 16 + kg * 8);
        vfc = ld_bf8(vtb + t0 + krow * 8);
        f32x16 ci = *(const f32x16*)(biasC + (t0 >> 5) * 32 + kg * 16);
        f32x16 sc = __builtin_amdgcn_mfma_f32_32x32x16_bf16(khc, qfl, ci, 0, 0, 0);
        sc = __builtin_amdgcn_mfma_f32_32x32x16_bf16(klc, qfh, sc, 0, 0, 0);
        sc = __builtin_amdgcn_mfma_f32_32x32x16_bf16(khc, qfh, sc, 0, 0, 0);
#pragma unroll
        for (int rg = 0; rg < 4; rg++) {
            float e0 = __builtin_amdgcn_exp2f(sc[rg * 4 + 0] - mrow);
            float e1 = __builtin_amdgcn_exp2f(sc[rg * 4 + 1] - mrow);
            float e2 = __builtin_amdgcn_exp2f(sc[rg * 4 + 2] - mrow);
            float e3 = __builtin_amdgcn_exp2f(sc[rg * 4 + 3] - mrow);
            lacc += (e0 + e1) + (e2 + e3);
            u32x2 pk;
            pk[0] = __builtin_amdgcn_perm(__builtin_bit_cast(u32, e1),
                                          __builtin_bit_cast(u32, e0), 0x07060302u);
            pk[1] = __builtin_amdgcn_perm(__builtin_bit_cast(u32, e3),
                                          __builtin_bit_cast(u32, e2), 0x07060302u);
            *(u32x2*)(pwb + ((rg ^ msw) * 8)) = pk;
        }
        p0c = *(const bf16x8*)pr0;
        p1c = *(const bf16x8*)pr1;
        khc = khn; klc = kln;
    }

    for (int t = t0 + 32; t < t0 + 512; t += 32) {
        int tn = (t + 32 < t0 + 512) ? (t + 32) : t0;
        bf16x8 khn = ld_bf8(kbh + (size_t)(tn + m) * 16 + kg * 8);
        bf16x8 kln = ld_bf8(kbl + (size_t)(tn + m) * 16 + kg * 8);
        bf16x8 vfn = ld_bf8(vtb + t + krow * 8);

        // PV for the PREVIOUS tile (overlaps this tile's score chain)
        o0 = __builtin_amdgcn_mfma_f32_16x16x32_bf16(p0c, vfc, o0, 0, 0, 0);
        o1 = __builtin_amdgcn_mfma_f32_16x16x32_bf16(p1c, vfc, o1, 0, 0, 0);

        f32x16 ci = *(const f32x16*)(biasC + (t >> 5) * 32 + kg * 16);
        f32x16 sc = __builtin_amdgcn_mfma_f32_32x32x16_bf16(khc, qfl, ci, 0, 0, 0);
        sc = __builtin_amdgcn_mfma_f32_32x32x16_bf16(klc, qfh, sc, 0, 0, 0);
        sc = __builtin_amdgcn_mfma_f32_32x32x16_bf16(khc, qfh, sc, 0, 0, 0);
#pragma unroll
        for (int rg = 0; rg < 4; rg++) {
            float e0 = __builtin_amdgcn_exp2f(sc[rg * 4 + 0] - mrow);
            float e1 = __builtin_amdgcn_exp2f(sc[rg * 4 + 1] - mrow);
            float e2 = __builtin_amdgcn_exp2f(sc[rg * 4 + 2] - mrow);
            float e3 = __builtin_amdgcn_exp2f(sc[rg * 4 + 3] - mrow);
            lacc += (e0 + e1) + (e2 + e3);
            u32x2 pk;
            pk[0] = __builtin_amdgcn_perm(__builtin_bit_cast(u32, e1),
                                          __builtin_bit_cast(u32, e0), 0x07060302u);
            pk[1] = __builtin_amdgcn_perm(__builtin_bit_cast(u32, e3),
                                          __builtin_bit_cast(u32, e2), 0x07060302u);
            *(u32x2*)(pwb + ((rg ^ msw) * 8)) = pk;
        }
        p0c = *(const bf16x8*)pr0;
        p1c = *(const bf16x8*)pr1;
        vfc = vfn; khc = khn; klc = kln;
    }

    // drain the pipeline: final tile's PV
    o0 = __builtin_amdgcn_mfma_f32_16x16x32_bf16(p0c, vfc, o0, 0, 0, 0);
    o1 = __builtin_amdgcn_mfma_f32_16x16x32_bf16(p1c, vfc, o1, 0, 0, 0);

    // lacc: per-lane sum over this lane's kg-half of the 512 keys
    lacc += __shfl_xor(lacc, 32, 64);

    __syncthreads();     // all P-tile/biasC reads done before alias writes

    *(f32x4*)(obuf + wave * 512 + q16 * 32 + krow * 4)      = o0;
    *(f32x4*)(obuf + wave * 512 + q16 * 32 + krow * 4 + 16) = o1;
    if (kg == 0) lbuf[wave * 32 + m] = lacc;
    __syncthreads();

    int dd = threadIdx.x & 15, q = threadIdx.x >> 4;
    int slot0 = (h == 0) ? 0 : h + 1;
#pragma unroll
    for (int hf = 0; hf < 2; hf++) {
        int qq = q + hf * 16;
        float os = obuf[0 * 512 + dd * 32 + qq] + obuf[1 * 512 + dd * 32 + qq]
                 + obuf[2 * 512 + dd * 32 + qq] + obuf[3 * 512 + dd * 32 + qq];
        float ls = lbuf[0 * 32 + qq] + lbuf[1 * 32 + qq]
                 + lbuf[2 * 32 + qq] + lbuf[3 * 32 + qq];
        u16 vb = f2b_rne(os * __builtin_amdgcn_rcpf(ls));
        int orow = b * 2048 + qs + qq;
        AO[orow * 128 + slot0 * 16 + dd] = vb;
        if (h == 1) AO[orow * 128 + 16 + dd] = vb;
    }
}

// ---------------------------------------------------------------------------
// final linear: out = AO(bf16) @ lin_w^T + lin_b (lin_w converted in-reg).
// ---------------------------------------------------------------------------
__global__ __launch_bounds__(256) void fin_kernel(
    const u16* __restrict__ AO, const float* __restrict__ lw,
    const float* __restrict__ lb, float* out)
{
    int ct   = threadIdx.x >> 6;
    int lane = threadIdx.x & 63;
    int m = lane & 31, kg = lane >> 5;
    int r0 = blockIdx.x * 32;
    int c = ct * 32 + m;

    f32x16 acc = zero16();
#pragma unroll 4
    for (int kk = 0; kk < 128; kk += 16) {
        bf16x8 af = ld_bf8(AO + (size_t)(r0 + m) * 128 + kk + kg * 8);
        const float* wp = lw + (size_t)c * 128 + kk + kg * 8;
        f32x4 w0 = *(const f32x4*)wp;
        f32x4 w1 = *(const f32x4*)(wp + 4);
        BF8 bfr;
#pragma unroll
        for (int j = 0; j < 4; j++) {
            bfr.s[j]     = f2b_rne(w0[j]);
            bfr.s[4 + j] = f2b_rne(w1[j]);
        }
        acc = __builtin_amdgcn_mfma_f32_32x32x16_bf16(af, bfr.v, acc, 0, 0, 0);
    }
    float bias = lb[c];
#pragma unroll
    for (int r = 0; r < 16; r++) {
        int row = (r & 3) + 8 * (r >> 2) + 4 * kg;
        out[(size_t)(r0 + row) * 128 + c] = acc[r] + bias;
    }
}

// ---------------------------------------------------------------------------
extern "C" void kernel_launch(void* const* d_in, const int* in_sizes, int n_in,
                              void* d_out, int out_size, void* d_ws, size_t ws_size,
                              hipStream_t stream)
{
    const float* x    = (const float*)d_in[0];
    const int*   mask = (const int*)d_in[1];
    const float* wq   = (const float*)d_in[2];
    const float* wk   = (const float*)d_in[3];
    const float* wv   = (const float*)d_in[4];
    const float* lw   = (const float*)d_in[5];
    const float* lb   = (const float*)d_in[6];
    float* out = (float*)d_out;

    char* ws = (char*)d_ws;
    u16* Qph = (u16*)(ws + 0 * 2097152);
    u16* Qpl = (u16*)(ws + 1 * 2097152);
    u16* Kph = (u16*)(ws + 2 * 2097152);
    u16* Kpl = (u16*)(ws + 3 * 2097152);
    u16* VT  = (u16*)(ws + 4 * 2097152);
    u16* AO  = (u16*)(ws + 5 * 2097152);

    proj_kernel<<<dim3(256, 3), 256, 0, stream>>>(x, wq, wk, wv,
                                                  Qph, Qpl, Kph, Kpl, VT);
    attn_kernel<<<1792, 256, 0, stream>>>(Qph, Qpl, Kph, Kpl, VT, mask, AO);
    fin_kernel<<<256, 256, 0, stream>>>(AO, lw, lb, out);
}

// Round 10
// 141.739 us; speedup vs baseline: 10.0637x; 1.0907x over previous
//
#include <hip/hip_runtime.h>
#include <stdint.h>

typedef unsigned short u16;
typedef unsigned int   u32;
typedef float   f32x4  __attribute__((ext_vector_type(4)));
typedef float   f32x16 __attribute__((ext_vector_type(16)));
typedef __bf16  bf16x8 __attribute__((ext_vector_type(8)));
typedef u32     u32x4  __attribute__((ext_vector_type(4)));
typedef u32     u32x2  __attribute__((ext_vector_type(2)));

union BF8 { bf16x8 v; u16 s[8]; u32x4 q; };

__device__ __forceinline__ u16 f2b_rne(float f) {
    u32 u = __builtin_bit_cast(u32, f);
    u32 r = u + 0x7FFFu + ((u >> 16) & 1u);
    return (u16)(r >> 16);
}
__device__ __forceinline__ u16 f2b_trunc(float f) {
    return (u16)(__builtin_bit_cast(u32, f) >> 16);
}
__device__ __forceinline__ float b2f(u16 h) {
    u32 u = ((u32)h) << 16;
    return __builtin_bit_cast(float, u);
}
__device__ __forceinline__ bf16x8 ld_bf8(const u16* p) {
    BF8 t; t.q = *(const u32x4*)p; return t.v;
}
__device__ __forceinline__ f32x16 zero16() {
    f32x16 z;
#pragma unroll
    for (int i = 0; i < 16; i++) z[i] = 0.f;
    return z;
}
__device__ __forceinline__ f32x4 zero4() {
    f32x4 z;
#pragma unroll
    for (int i = 0; i < 4; i++) z[i] = 0.f;
    return z;
}

#define SCALE2 0.1275312959479341f        /* log2(e)/sqrt(128) */
#define MBIAS2 -1442.6950408889634f       /* -1000*log2(e) */

// ---------------------------------------------------------------------------
// projection: W columns read coalesced and hi/lo split in-reg. Q/K written
// hi/lo head-packed [b][h][s][16] (Q pre-scaled); V written transposed
// VT[b*128+n][s]. The V-branch's first 32 blocks also fill biasG: the soft
// mask bias pre-permuted into MFMA C-layout, kept in GLOBAL memory (32 KB,
// L1/L2-resident) so attn's C-operand loads ride the VMEM pipe, not LDS.
// grid (256,3) x 256.
// ---------------------------------------------------------------------------
__global__ __launch_bounds__(256) void proj_kernel(
    const float* __restrict__ x, const float* __restrict__ wq,
    const float* __restrict__ wk, const float* __restrict__ wv,
    const int* __restrict__ mask,
    u16* Qph, u16* Qpl, u16* Kph, u16* Kpl, u16* VT, float* biasG)
{
    int typ  = blockIdx.y;                 // 0=Q 1=K 2=V
    int ct   = threadIdx.x >> 6;
    int lane = threadIdx.x & 63;
    int m = lane & 31, kg = lane >> 5;
    int r0 = blockIdx.x * 32;
    int c = ct * 32 + m;

    const float* wp = (typ == 0) ? wq : (typ == 1) ? wk : wv;

    f32x16 acc = zero16();
#pragma unroll 4
    for (int kk = 0; kk < 128; kk += 16) {
        const float* xp = x + (size_t)(r0 + m) * 128 + kk + kg * 8;
        f32x4 x0 = *(const f32x4*)xp;
        f32x4 x1 = *(const f32x4*)(xp + 4);
        BF8 ah, al;
#pragma unroll
        for (int j = 0; j < 4; j++) {
            u16 hb = f2b_trunc(x0[j]);
            ah.s[j] = hb; al.s[j] = f2b_trunc(x0[j] - b2f(hb));
            u16 hb2 = f2b_trunc(x1[j]);
            ah.s[4 + j] = hb2; al.s[4 + j] = f2b_trunc(x1[j] - b2f(hb2));
        }
        const float* wcol = wp + (size_t)(kk + kg * 8) * 128 + c;
        if (typ < 2) {
            BF8 bh, bl_;
#pragma unroll
            for (int j = 0; j < 8; j++) {
                float w = wcol[(size_t)j * 128];
                u16 hb = f2b_trunc(w);
                bh.s[j] = hb; bl_.s[j] = f2b_trunc(w - b2f(hb));
            }
            acc = __builtin_amdgcn_mfma_f32_32x32x16_bf16(ah.v, bh.v, acc, 0, 0, 0);
            acc = __builtin_amdgcn_mfma_f32_32x32x16_bf16(ah.v, bl_.v, acc, 0, 0, 0);
            acc = __builtin_amdgcn_mfma_f32_32x32x16_bf16(al.v, bh.v, acc, 0, 0, 0);
        } else {
            BF8 bh;
#pragma unroll
            for (int j = 0; j < 8; j++) bh.s[j] = f2b_rne(wcol[(size_t)j * 128]);
            acc = __builtin_amdgcn_mfma_f32_32x32x16_bf16(ah.v, bh.v, acc, 0, 0, 0);
        }
    }

    int b = r0 >> 11, sl = r0 & 2047;
    if (typ < 2) {
        u16* H = typ ? Kph : Qph;
        u16* L = typ ? Kpl : Qpl;
        int hh = c >> 4, d = c & 15;
        if (hh == 7) return;                      // head 7 never consumed
        float scl = (typ == 0) ? SCALE2 : 1.0f;
        size_t hb_off = (size_t)(b * 8 + hh) * 2048 * 16 + d;
#pragma unroll
        for (int r = 0; r < 16; r++) {
            int row = (r & 3) + 8 * (r >> 2) + 4 * kg;
            float v = acc[r] * scl;
            u16 hi = f2b_trunc(v);
            size_t idx = hb_off + (size_t)(sl + row) * 16;
            H[idx] = hi;
            L[idx] = f2b_trunc(v - b2f(hi));
        }
    } else {
        // biasG fill: entry e = b*2048 + tile*32 + kg*16 + r maps to
        // key = tile*32 + (r&3)+8*(r>>2)+4*kg  (MFMA C-layout)
        if (blockIdx.x < 32) {
            int e = blockIdx.x * 256 + threadIdx.x;
            int r = e & 15, kgg = (e >> 4) & 1, ti = (e >> 5) & 63, bb = e >> 11;
            int key = ti * 32 + (r & 3) + 8 * (r >> 2) + 4 * kgg;
            biasG[e] = (mask[bb * 2048 + key] != 0) ? 0.0f : MBIAS2;
        }
        if ((c >> 4) == 7) return;
#pragma unroll
        for (int rg = 0; rg < 4; rg++) {
            int rowb = rg * 8 + 4 * kg;
            BF8 pk;
#pragma unroll
            for (int q = 0; q < 4; q++) pk.s[q] = f2b_rne(acc[rg * 4 + q]);
            u32x4 tmp = pk.q;
            *(u32*)(VT + (size_t)(b * 128 + c) * 2048 + sl + rowb)     = tmp[0];
            *(u32*)(VT + (size_t)(b * 128 + c) * 2048 + sl + rowb + 2) = tmp[1];
        }
    }
}

// ---------------------------------------------------------------------------
// fused attention (R7 structure; bias table moved LDS -> global):
//  - S^T orientation (lane = query, keys in regs); bias C-operand loaded
//    per tile from the L1-resident biasG table via VMEM (was 4x
//    ds_read_b128/tile on the saturated LDS pipe).
//  - two passes (approx max then exact), ones-MFMA row-sum (consistent with
//    the bf16 P numerator), K prefetch, NO PV pipeline (spilled in R8/R9).
//  - pbuf stride 32 u16 + XOR block swizzle (all 16B-aligned).
//  - LDS 9.2 KB; 7 blocks/CU resident (grid 1792 = 7x256).
// ---------------------------------------------------------------------------
__global__ __launch_bounds__(256, 7) void attn_kernel(
    const u16* __restrict__ Qph, const u16* __restrict__ Qpl,
    const u16* __restrict__ Kph, const u16* __restrict__ Kpl,
    const u16* __restrict__ VT, const float* __restrict__ biasG, u16* AO)
{
    __shared__ char smem[9216];
    u16*   pbuf  = (u16*)smem;               // [4][32][32] u16 = 8192 B (swizzled)
    float* lbuf  = (float*)(smem + 8192);    // [4][32] f32 = 512 B
    float* lsmax = (float*)(smem + 8704);    // [32][4] = 512 B
    float* obuf  = (float*)smem;             // [4][16][32] f32, aliases pbuf

    int bid = blockIdx.x;
    int bh = bid % 28;
    int qt = bid / 28;
    int b = bh / 7, h = bh % 7;
    int wave = threadIdx.x >> 6, lane = threadIdx.x & 63;
    int m = lane & 31, kg = lane >> 5;
    int qs = qt * 32;

    size_t headoff = (size_t)(b * 8 + h) * 2048 * 16;
    bf16x8 qfh = ld_bf8(Qph + headoff + (size_t)(qs + m) * 16 + kg * 8);
    bf16x8 qfl = ld_bf8(Qpl + headoff + (size_t)(qs + m) * 16 + kg * 8);
    const u16* kbh = Kph + headoff;
    const u16* kbl = Kpl + headoff;
    const float* bgb = biasG + (size_t)b * 2048 + kg * 16;   // + tile*32 + r

    int t0 = wave * 512;

    // ---- pass 1: per-query max of approx biased scores (K hi x Q hi + bias) ----
    float mloc = -3.0e38f;
    {
        bf16x8 khc = ld_bf8(kbh + (size_t)(t0 + m) * 16 + kg * 8);
        for (int t = t0; t < t0 + 512; t += 32) {
            int tn = (t + 32 < t0 + 512) ? (t + 32) : t0;
            bf16x8 khn = ld_bf8(kbh + (size_t)(tn + m) * 16 + kg * 8);
            f32x16 ci = *(const f32x16*)(bgb + (t >> 5) * 32);
            f32x16 sc = __builtin_amdgcn_mfma_f32_32x32x16_bf16(khc, qfh, ci, 0, 0, 0);
#pragma unroll
            for (int r = 0; r < 16; r += 2)       // paired for v_max3 fusion
                mloc = fmaxf(fmaxf(mloc, sc[r]), sc[r + 1]);
            khc = khn;
        }
    }
    mloc = fmaxf(mloc, __shfl_xor(mloc, 32, 64));
    if (kg == 0) lsmax[m * 4 + wave] = mloc;
    __syncthreads();
    f32x4 mv = *(const f32x4*)(lsmax + m * 4);
    float mrow = fmaxf(fmaxf(mv[0], mv[1]), fmaxf(mv[2], mv[3]));  // per-lane (query m)

    // ---- pass 2: exact biased scores -> exp2 -> swizzled P tile -> PV + ones ----
    f32x4 o0 = zero4(), o1 = zero4(), l0 = zero4(), l1 = zero4();
    BF8 onesu;
#pragma unroll
    for (int j = 0; j < 8; j++) onesu.s[j] = 0x3F80;
    bf16x8 ones = onesu.v;

    int q16 = lane & 15, krow = lane >> 4;
    const u16* vtb = VT + (size_t)(b * 128 + h * 16 + q16) * 2048;
    int msw = (m >> 1) & 3;                                  // write swizzle
    int qsw = (q16 >> 1) & 3;                                // read swizzle
    u16* pwb = pbuf + wave * 1024 + m * 32 + kg * 4;
    const u16* pr0 = pbuf + wave * 1024 + q16 * 32 + ((krow ^ qsw) * 8);
    const u16* pr1 = pr0 + 16 * 32;

    bf16x8 khc = ld_bf8(kbh + (size_t)(t0 + m) * 16 + kg * 8);
    bf16x8 klc = ld_bf8(kbl + (size_t)(t0 + m) * 16 + kg * 8);

    for (int t = t0; t < t0 + 512; t += 32) {
        int tn = (t + 32 < t0 + 512) ? (t + 32) : t0;
        bf16x8 khn = ld_bf8(kbh + (size_t)(tn + m) * 16 + kg * 8);
        bf16x8 kln = ld_bf8(kbl + (size_t)(tn + m) * 16 + kg * 8);
        bf16x8 vf  = ld_bf8(vtb + t + krow * 8);

        f32x16 ci = *(const f32x16*)(bgb + (t >> 5) * 32);
        f32x16 sc = __builtin_amdgcn_mfma_f32_32x32x16_bf16(khc, qfl, ci, 0, 0, 0);
        sc = __builtin_amdgcn_mfma_f32_32x32x16_bf16(klc, qfh, sc, 0, 0, 0);
        sc = __builtin_amdgcn_mfma_f32_32x32x16_bf16(khc, qfh, sc, 0, 0, 0);
#pragma unroll
        for (int rg = 0; rg < 4; rg++) {
            float e0 = __builtin_amdgcn_exp2f(sc[rg * 4 + 0] - mrow);
            float e1 = __builtin_amdgcn_exp2f(sc[rg * 4 + 1] - mrow);
            float e2 = __builtin_amdgcn_exp2f(sc[rg * 4 + 2] - mrow);
            float e3 = __builtin_amdgcn_exp2f(sc[rg * 4 + 3] - mrow);
            u32x2 pk;
            pk[0] = __builtin_amdgcn_perm(__builtin_bit_cast(u32, e1),
                                          __builtin_bit_cast(u32, e0), 0x07060302u);
            pk[1] = __builtin_amdgcn_perm(__builtin_bit_cast(u32, e3),
                                          __builtin_bit_cast(u32, e2), 0x07060302u);
            *(u32x2*)(pwb + ((rg ^ msw) * 8)) = pk;   // keys rg*8+4kg..+3, query m
        }
        bf16x8 p0 = *(const bf16x8*)pr0;
        bf16x8 p1 = *(const bf16x8*)pr1;
        o0 = __builtin_amdgcn_mfma_f32_16x16x32_bf16(p0, vf, o0, 0, 0, 0);
        o1 = __builtin_amdgcn_mfma_f32_16x16x32_bf16(p1, vf, o1, 0, 0, 0);
        l0 = __builtin_amdgcn_mfma_f32_16x16x32_bf16(p0, ones, l0, 0, 0, 0);
        l1 = __builtin_amdgcn_mfma_f32_16x16x32_bf16(p1, ones, l1, 0, 0, 0);
        khc = khn; klc = kln;
    }

    __syncthreads();     // all P-tile reads done before obuf alias writes

    *(f32x4*)(obuf + wave * 512 + q16 * 32 + krow * 4)      = o0;
    *(f32x4*)(obuf + wave * 512 + q16 * 32 + krow * 4 + 16) = o1;
    if (q16 == 0) {
        *(f32x4*)(lbuf + wave * 32 + krow * 4)      = l0;
        *(f32x4*)(lbuf + wave * 32 + krow * 4 + 16) = l1;
    }
    __syncthreads();

    int dd = threadIdx.x & 15, q = threadIdx.x >> 4;
    int slot0 = (h == 0) ? 0 : h + 1;
#pragma unroll
    for (int hf = 0; hf < 2; hf++) {
        int qq = q + hf * 16;
        float os = obuf[0 * 512 + dd * 32 + qq] + obuf[1 * 512 + dd * 32 + qq]
                 + obuf[2 * 512 + dd * 32 + qq] + obuf[3 * 512 + dd * 32 + qq];
        float ls = lbuf[0 * 32 + qq] + lbuf[1 * 32 + qq]
                 + lbuf[2 * 32 + qq] + lbuf[3 * 32 + qq];
        u16 vb = f2b_rne(os * __builtin_amdgcn_rcpf(ls));
        int orow = b * 2048 + qs + qq;
        AO[orow * 128 + slot0 * 16 + dd] = vb;
        if (h == 1) AO[orow * 128 + 16 + dd] = vb;
    }
}

// ---------------------------------------------------------------------------
// final linear: out = AO(bf16) @ lin_w^T + lin_b (lin_w converted in-reg).
// ---------------------------------------------------------------------------
__global__ __launch_bounds__(256) void fin_kernel(
    const u16* __restrict__ AO, const float* __restrict__ lw,
    const float* __restrict__ lb, float* out)
{
    int ct   = threadIdx.x >> 6;
    int lane = threadIdx.x & 63;
    int m = lane & 31, kg = lane >> 5;
    int r0 = blockIdx.x * 32;
    int c = ct * 32 + m;

    f32x16 acc = zero16();
#pragma unroll 4
    for (int kk = 0; kk < 128; kk += 16) {
        bf16x8 af = ld_bf8(AO + (size_t)(r0 + m) * 128 + kk + kg * 8);
        const float* wp = lw + (size_t)c * 128 + kk + kg * 8;
        f32x4 w0 = *(const f32x4*)wp;
        f32x4 w1 = *(const f32x4*)(wp + 4);
        BF8 bfr;
#pragma unroll
        for (int j = 0; j < 4; j++) {
            bfr.s[j]     = f2b_rne(w0[j]);
            bfr.s[4 + j] = f2b_rne(w1[j]);
        }
        acc = __builtin_amdgcn_mfma_f32_32x32x16_bf16(af, bfr.v, acc, 0, 0, 0);
    }
    float bias = lb[c];
#pragma unroll
    for (int r = 0; r < 16; r++) {
        int row = (r & 3) + 8 * (r >> 2) + 4 * kg;
        out[(size_t)(r0 + row) * 128 + c] = acc[r] + bias;
    }
}

// ---------------------------------------------------------------------------
extern "C" void kernel_launch(void* const* d_in, const int* in_sizes, int n_in,
                              void* d_out, int out_size, void* d_ws, size_t ws_size,
                              hipStream_t stream)
{
    const float* x    = (const float*)d_in[0];
    const int*   mask = (const int*)d_in[1];
    const float* wq   = (const float*)d_in[2];
    const float* wk   = (const float*)d_in[3];
    const float* wv   = (const float*)d_in[4];
    const float* lw   = (const float*)d_in[5];
    const float* lb   = (const float*)d_in[6];
    float* out = (float*)d_out;

    char* ws = (char*)d_ws;
    u16*   Qph   = (u16*)(ws + 0 * 2097152);
    u16*   Qpl   = (u16*)(ws + 1 * 2097152);
    u16*   Kph   = (u16*)(ws + 2 * 2097152);
    u16*   Kpl   = (u16*)(ws + 3 * 2097152);
    u16*   VT    = (u16*)(ws + 4 * 2097152);
    u16*   AO    = (u16*)(ws + 5 * 2097152);
    float* biasG = (float*)(ws + 6 * 2097152);

    proj_kernel<<<dim3(256, 3), 256, 0, stream>>>(x, wq, wk, wv, mask,
                                                  Qph, Qpl, Kph, Kpl, VT, biasG);
    attn_kernel<<<1792, 256, 0, stream>>>(Qph, Qpl, Kph, Kpl, VT, biasG, AO);
    fin_kernel<<<256, 256, 0, stream>>>(AO, lw, lb, out);
}

// Round 12
// 129.337 us; speedup vs baseline: 11.0288x; 1.0959x over previous
//
#include <hip/hip_runtime.h>
#include <stdint.h>

typedef unsigned short u16;
typedef unsigned int   u32;
typedef float   f32x4  __attribute__((ext_vector_type(4)));
typedef float   f32x16 __attribute__((ext_vector_type(16)));
typedef __bf16  bf16x8 __attribute__((ext_vector_type(8)));
typedef u32     u32x4  __attribute__((ext_vector_type(4)));
typedef u32     u32x2  __attribute__((ext_vector_type(2)));

union BF8 { bf16x8 v; u16 s[8]; u32x4 q; };

__device__ __forceinline__ u16 f2b_rne(float f) {
    u32 u = __builtin_bit_cast(u32, f);
    u32 r = u + 0x7FFFu + ((u >> 16) & 1u);
    return (u16)(r >> 16);
}
__device__ __forceinline__ u16 f2b_trunc(float f) {
    return (u16)(__builtin_bit_cast(u32, f) >> 16);
}
__device__ __forceinline__ float b2f(u16 h) {
    u32 u = ((u32)h) << 16;
    return __builtin_bit_cast(float, u);
}
__device__ __forceinline__ bf16x8 ld_bf8(const u16* p) {
    BF8 t; t.q = *(const u32x4*)p; return t.v;
}
__device__ __forceinline__ f32x16 zero16() {
    f32x16 z;
#pragma unroll
    for (int i = 0; i < 16; i++) z[i] = 0.f;
    return z;
}
__device__ __forceinline__ f32x4 zero4() {
    f32x4 z;
#pragma unroll
    for (int i = 0; i < 4; i++) z[i] = 0.f;
    return z;
}

#define SCALE2 0.1275312959479341f        /* log2(e)/sqrt(128) */

// ---------------------------------------------------------------------------
// projection: W columns read coalesced and hi/lo split in-reg. Q/K written
// hi/lo head-packed [b][h][s][16] (Q pre-scaled); V written transposed
// VT[b*128+n][s]. grid (256,3) x 256.  (identical to R7's proven version)
// ---------------------------------------------------------------------------
__global__ __launch_bounds__(256) void proj_kernel(
    const float* __restrict__ x, const float* __restrict__ wq,
    const float* __restrict__ wk, const float* __restrict__ wv,
    u16* Qph, u16* Qpl, u16* Kph, u16* Kpl, u16* VT)
{
    int typ  = blockIdx.y;                 // 0=Q 1=K 2=V
    int ct   = threadIdx.x >> 6;
    int lane = threadIdx.x & 63;
    int m = lane & 31, kg = lane >> 5;
    int r0 = blockIdx.x * 32;
    int c = ct * 32 + m;

    const float* wp = (typ == 0) ? wq : (typ == 1) ? wk : wv;

    f32x16 acc = zero16();
#pragma unroll 4
    for (int kk = 0; kk < 128; kk += 16) {
        const float* xp = x + (size_t)(r0 + m) * 128 + kk + kg * 8;
        f32x4 x0 = *(const f32x4*)xp;
        f32x4 x1 = *(const f32x4*)(xp + 4);
        BF8 ah, al;
#pragma unroll
        for (int j = 0; j < 4; j++) {
            u16 hb = f2b_trunc(x0[j]);
            ah.s[j] = hb; al.s[j] = f2b_trunc(x0[j] - b2f(hb));
            u16 hb2 = f2b_trunc(x1[j]);
            ah.s[4 + j] = hb2; al.s[4 + j] = f2b_trunc(x1[j] - b2f(hb2));
        }
        const float* wcol = wp + (size_t)(kk + kg * 8) * 128 + c;
        if (typ < 2) {
            BF8 bh, bl_;
#pragma unroll
            for (int j = 0; j < 8; j++) {
                float w = wcol[(size_t)j * 128];
                u16 hb = f2b_trunc(w);
                bh.s[j] = hb; bl_.s[j] = f2b_trunc(w - b2f(hb));
            }
            acc = __builtin_amdgcn_mfma_f32_32x32x16_bf16(ah.v, bh.v, acc, 0, 0, 0);
            acc = __builtin_amdgcn_mfma_f32_32x32x16_bf16(ah.v, bl_.v, acc, 0, 0, 0);
            acc = __builtin_amdgcn_mfma_f32_32x32x16_bf16(al.v, bh.v, acc, 0, 0, 0);
        } else {
            BF8 bh;
#pragma unroll
            for (int j = 0; j < 8; j++) bh.s[j] = f2b_rne(wcol[(size_t)j * 128]);
            acc = __builtin_amdgcn_mfma_f32_32x32x16_bf16(ah.v, bh.v, acc, 0, 0, 0);
        }
    }

    int b = r0 >> 11, sl = r0 & 2047;
    if (typ < 2) {
        u16* H = typ ? Kph : Qph;
        u16* L = typ ? Kpl : Qpl;
        int hh = c >> 4, d = c & 15;
        if (hh == 7) return;                      // head 7 never consumed
        float scl = (typ == 0) ? SCALE2 : 1.0f;
        size_t hb_off = (size_t)(b * 8 + hh) * 2048 * 16 + d;
#pragma unroll
        for (int r = 0; r < 16; r++) {
            int row = (r & 3) + 8 * (r >> 2) + 4 * kg;
            float v = acc[r] * scl;
            u16 hi = f2b_trunc(v);
            size_t idx = hb_off + (size_t)(sl + row) * 16;
            H[idx] = hi;
            L[idx] = f2b_trunc(v - b2f(hi));
        }
    } else {
        if ((c >> 4) == 7) return;
#pragma unroll
        for (int rg = 0; rg < 4; rg++) {
            int rowb = rg * 8 + 4 * kg;
            BF8 pk;
#pragma unroll
            for (int q = 0; q < 4; q++) pk.s[q] = f2b_rne(acc[rg * 4 + q]);
            u32x4 tmp = pk.q;
            *(u32*)(VT + (size_t)(b * 128 + c) * 2048 + sl + rowb)     = tmp[0];
            *(u32*)(VT + (size_t)(b * 128 + c) * 2048 + sl + rowb + 2) = tmp[1];
        }
    }
}

// ---------------------------------------------------------------------------
// fused attention (R11 structure, mask POLARITY FIXED):
//  - bias[key][q] = is_masked[key] * (-1442.695) is rank-1 -> ONE MFMA:
//    sc = mfma(kmask, qbias, 0); kmask = bf16 1.0 where mask==0 (MASKED —
//    R11 had this inverted), in k-slots 0..2; qbias = 3-term bf16 split
//    {-1440, -2.6875, -0.00753784} (sum -1442.69504, err 5e-6).
//  - replaces 4 ds_read_b128/tile (R7) or spilling global ci loads (R10)
//    with 1 broadcast ds_read_u16 + ~3 VALU + 1 MFMA; removes the 16-VGPR
//    C-operand live range that drove R8-R10's scratch spills.
//  - two passes (approx max, exact), K prefetch, ones-MFMA row-sum,
//    stride-32 XOR-swizzled pbuf, 7 blocks/CU (grid 1792).
// ---------------------------------------------------------------------------
__global__ __launch_bounds__(256, 7) void attn_kernel(
    const u16* __restrict__ Qph, const u16* __restrict__ Qpl,
    const u16* __restrict__ Kph, const u16* __restrict__ Kpl,
    const u16* __restrict__ VT, const int* __restrict__ mask, u16* AO)
{
    __shared__ char smem[13312];
    u16*   pbuf  = (u16*)smem;               // [4][32][32] u16 = 8192 B (swizzled)
    u16*   m01   = (u16*)(smem + 8192);      // [2048] bf16 masked-flag = 4096 B
    float* lbuf  = (float*)(smem + 12288);   // [4][32] f32 = 512 B
    float* lsmax = (float*)(smem + 12800);   // [32][4] = 512 B
    float* obuf  = (float*)smem;             // [4][16][32] f32, aliases pbuf

    int bid = blockIdx.x;
    int bh = bid % 28;
    int qt = bid / 28;
    int b = bh / 7, h = bh % 7;
    int wave = threadIdx.x >> 6, lane = threadIdx.x & 63;
    int m = lane & 31, kg = lane >> 5;
    int qs = qt * 32;

    // ---- stage m01: bf16 1.0 where key is MASKED (mask == 0) ----
    {
        int t8 = threadIdx.x * 8;
        const int* mp = mask + b * 2048 + t8;
        BF8 pk;
#pragma unroll
        for (int j = 0; j < 8; j++) pk.s[j] = (mp[j] == 0) ? (u16)0x3F80 : (u16)0;
        *(u32x4*)(m01 + t8) = pk.q;
    }
    __syncthreads();

    // qbias: k-slots 0..2 = {-1440, -2.6875, -0.00753784} on kg=0 lanes
    u32 kgz = (kg == 0) ? 0xFFFFFFFFu : 0u;
    BF8 qb;
    qb.q[0] = 0xC02CC4B4u & kgz;     // s0=-1440 (0xC4B4), s1=-2.6875 (0xC02C)
    qb.q[1] = 0x0000BBF7u & kgz;     // s2=-0.00753784 (0xBBF7)
    qb.q[2] = 0; qb.q[3] = 0;

    size_t headoff = (size_t)(b * 8 + h) * 2048 * 16;
    bf16x8 qfh = ld_bf8(Qph + headoff + (size_t)(qs + m) * 16 + kg * 8);
    bf16x8 qfl = ld_bf8(Qpl + headoff + (size_t)(qs + m) * 16 + kg * 8);
    const u16* kbh = Kph + headoff;
    const u16* kbl = Kpl + headoff;

    int t0 = wave * 512;

    // ---- pass 1: per-query max of approx biased scores (bias-MFMA + Khi*Qhi) ----
    float mloc = -3.0e38f;
    {
        bf16x8 khc = ld_bf8(kbh + (size_t)(t0 + m) * 16 + kg * 8);
        for (int t = t0; t < t0 + 512; t += 32) {
            int tn = (t + 32 < t0 + 512) ? (t + 32) : t0;
            bf16x8 khn = ld_bf8(kbh + (size_t)(tn + m) * 16 + kg * 8);
            u32 mv_ = (u32)m01[t + m] & kgz;
            BF8 km;
            km.q[0] = __builtin_amdgcn_perm(mv_, mv_, 0x05040100u);
            km.q[1] = mv_; km.q[2] = 0; km.q[3] = 0;
            f32x16 sc = __builtin_amdgcn_mfma_f32_32x32x16_bf16(km.v, qb.v, zero16(), 0, 0, 0);
            sc = __builtin_amdgcn_mfma_f32_32x32x16_bf16(khc, qfh, sc, 0, 0, 0);
#pragma unroll
            for (int r = 0; r < 16; r += 2)       // paired for v_max3 fusion
                mloc = fmaxf(fmaxf(mloc, sc[r]), sc[r + 1]);
            khc = khn;
        }
    }
    mloc = fmaxf(mloc, __shfl_xor(mloc, 32, 64));
    if (kg == 0) lsmax[m * 4 + wave] = mloc;
    __syncthreads();
    f32x4 mv = *(const f32x4*)(lsmax + m * 4);
    float mrow = fmaxf(fmaxf(mv[0], mv[1]), fmaxf(mv[2], mv[3]));  // per-lane (query m)

    // ---- pass 2: exact biased scores -> exp2 -> swizzled P tile -> PV + ones ----
    f32x4 o0 = zero4(), o1 = zero4(), l0 = zero4(), l1 = zero4();
    BF8 onesu;
#pragma unroll
    for (int j = 0; j < 8; j++) onesu.s[j] = 0x3F80;
    bf16x8 ones = onesu.v;

    int q16 = lane & 15, krow = lane >> 4;
    const u16* vtb = VT + (size_t)(b * 128 + h * 16 + q16) * 2048;
    int msw = (m >> 1) & 3;                                  // write swizzle
    int qsw = (q16 >> 1) & 3;                                // read swizzle
    u16* pwb = pbuf + wave * 1024 + m * 32 + kg * 4;
    const u16* pr0 = pbuf + wave * 1024 + q16 * 32 + ((krow ^ qsw) * 8);
    const u16* pr1 = pr0 + 16 * 32;

    bf16x8 khc = ld_bf8(kbh + (size_t)(t0 + m) * 16 + kg * 8);
    bf16x8 klc = ld_bf8(kbl + (size_t)(t0 + m) * 16 + kg * 8);

    for (int t = t0; t < t0 + 512; t += 32) {
        int tn = (t + 32 < t0 + 512) ? (t + 32) : t0;
        bf16x8 khn = ld_bf8(kbh + (size_t)(tn + m) * 16 + kg * 8);
        bf16x8 kln = ld_bf8(kbl + (size_t)(tn + m) * 16 + kg * 8);
        bf16x8 vf  = ld_bf8(vtb + t + krow * 8);

        u32 mv_ = (u32)m01[t + m] & kgz;
        BF8 km;
        km.q[0] = __builtin_amdgcn_perm(mv_, mv_, 0x05040100u);
        km.q[1] = mv_; km.q[2] = 0; km.q[3] = 0;
        f32x16 sc = __builtin_amdgcn_mfma_f32_32x32x16_bf16(km.v, qb.v, zero16(), 0, 0, 0);
        sc = __builtin_amdgcn_mfma_f32_32x32x16_bf16(khc, qfl, sc, 0, 0, 0);
        sc = __builtin_amdgcn_mfma_f32_32x32x16_bf16(klc, qfh, sc, 0, 0, 0);
        sc = __builtin_amdgcn_mfma_f32_32x32x16_bf16(khc, qfh, sc, 0, 0, 0);
#pragma unroll
        for (int rg = 0; rg < 4; rg++) {
            float e0 = __builtin_amdgcn_exp2f(sc[rg * 4 + 0] - mrow);
            float e1 = __builtin_amdgcn_exp2f(sc[rg * 4 + 1] - mrow);
            float e2 = __builtin_amdgcn_exp2f(sc[rg * 4 + 2] - mrow);
            float e3 = __builtin_amdgcn_exp2f(sc[rg * 4 + 3] - mrow);
            u32x2 pk;
            pk[0] = __builtin_amdgcn_perm(__builtin_bit_cast(u32, e1),
                                          __builtin_bit_cast(u32, e0), 0x07060302u);
            pk[1] = __builtin_amdgcn_perm(__builtin_bit_cast(u32, e3),
                                          __builtin_bit_cast(u32, e2), 0x07060302u);
            *(u32x2*)(pwb + ((rg ^ msw) * 8)) = pk;   // keys rg*8+4kg..+3, query m
        }
        bf16x8 p0 = *(const bf16x8*)pr0;
        bf16x8 p1 = *(const bf16x8*)pr1;
        o0 = __builtin_amdgcn_mfma_f32_16x16x32_bf16(p0, vf, o0, 0, 0, 0);
        o1 = __builtin_amdgcn_mfma_f32_16x16x32_bf16(p1, vf, o1, 0, 0, 0);
        l0 = __builtin_amdgcn_mfma_f32_16x16x32_bf16(p0, ones, l0, 0, 0, 0);
        l1 = __builtin_amdgcn_mfma_f32_16x16x32_bf16(p1, ones, l1, 0, 0, 0);
        khc = khn; klc = kln;
    }

    __syncthreads();     // all P-tile reads done before obuf alias writes

    *(f32x4*)(obuf + wave * 512 + q16 * 32 + krow * 4)      = o0;
    *(f32x4*)(obuf + wave * 512 + q16 * 32 + krow * 4 + 16) = o1;
    if (q16 == 0) {
        *(f32x4*)(lbuf + wave * 32 + krow * 4)      = l0;
        *(f32x4*)(lbuf + wave * 32 + krow * 4 + 16) = l1;
    }
    __syncthreads();

    int dd = threadIdx.x & 15, q = threadIdx.x >> 4;
    int slot0 = (h == 0) ? 0 : h + 1;
#pragma unroll
    for (int hf = 0; hf < 2; hf++) {
        int qq = q + hf * 16;
        float os = obuf[0 * 512 + dd * 32 + qq] + obuf[1 * 512 + dd * 32 + qq]
                 + obuf[2 * 512 + dd * 32 + qq] + obuf[3 * 512 + dd * 32 + qq];
        float ls = lbuf[0 * 32 + qq] + lbuf[1 * 32 + qq]
                 + lbuf[2 * 32 + qq] + lbuf[3 * 32 + qq];
        u16 vb = f2b_rne(os * __builtin_amdgcn_rcpf(ls));
        int orow = b * 2048 + qs + qq;
        AO[orow * 128 + slot0 * 16 + dd] = vb;
        if (h == 1) AO[orow * 128 + 16 + dd] = vb;
    }
}

// ---------------------------------------------------------------------------
// final linear: out = AO(bf16) @ lin_w^T + lin_b (lin_w converted in-reg).
// ---------------------------------------------------------------------------
__global__ __launch_bounds__(256) void fin_kernel(
    const u16* __restrict__ AO, const float* __restrict__ lw,
    const float* __restrict__ lb, float* out)
{
    int ct   = threadIdx.x >> 6;
    int lane = threadIdx.x & 63;
    int m = lane & 31, kg = lane >> 5;
    int r0 = blockIdx.x * 32;
    int c = ct * 32 + m;

    f32x16 acc = zero16();
#pragma unroll 4
    for (int kk = 0; kk < 128; kk += 16) {
        bf16x8 af = ld_bf8(AO + (size_t)(r0 + m) * 128 + kk + kg * 8);
        const float* wp = lw + (size_t)c * 128 + kk + kg * 8;
        f32x4 w0 = *(const f32x4*)wp;
        f32x4 w1 = *(const f32x4*)(wp + 4);
        BF8 bfr;
#pragma unroll
        for (int j = 0; j < 4; j++) {
            bfr.s[j]     = f2b_rne(w0[j]);
            bfr.s[4 + j] = f2b_rne(w1[j]);
        }
        acc = __builtin_amdgcn_mfma_f32_32x32x16_bf16(af, bfr.v, acc, 0, 0, 0);
    }
    float bias = lb[c];
#pragma unroll
    for (int r = 0; r < 16; r++) {
        int row = (r & 3) + 8 * (r >> 2) + 4 * kg;
        out[(size_t)(r0 + row) * 128 + c] = acc[r] + bias;
    }
}

// ---------------------------------------------------------------------------
extern "C" void kernel_launch(void* const* d_in, const int* in_sizes, int n_in,
                              void* d_out, int out_size, void* d_ws, size_t ws_size,
                              hipStream_t stream)
{
    const float* x    = (const float*)d_in[0];
    const int*   mask = (const int*)d_in[1];
    const float* wq   = (const float*)d_in[2];
    const float* wk   = (const float*)d_in[3];
    const float* wv   = (const float*)d_in[4];
    const float* lw   = (const float*)d_in[5];
    const float* lb   = (const float*)d_in[6];
    float* out = (float*)d_out;

    char* ws = (char*)d_ws;
    u16* Qph = (u16*)(ws + 0 * 2097152);
    u16* Qpl = (u16*)(ws + 1 * 2097152);
    u16* Kph = (u16*)(ws + 2 * 2097152);
    u16* Kpl = (u16*)(ws + 3 * 2097152);
    u16* VT  = (u16*)(ws + 4 * 2097152);
    u16* AO  = (u16*)(ws + 5 * 2097152);

    proj_kernel<<<dim3(256, 3), 256, 0, stream>>>(x, wq, wk, wv,
                                                  Qph, Qpl, Kph, Kpl, VT);
    attn_kernel<<<1792, 256, 0, stream>>>(Qph, Qpl, Kph, Kpl, VT, mask, AO);
    fin_kernel<<<256, 256, 0, stream>>>(AO, lw, lb, out);
}